// Round 21
// baseline (332.821 us; speedup 1.0000x reference)
//
#include <hip/hip_runtime.h>

// LiquidNeuralNetwork: B=512, S=1024, IN=16, HID=64, OUT=1.
// r20 (Picard NPIC=2, rank-1 sweep-1, MFMA sweep-2, conflict-free strides):
// 277us dispatch, session best. Counters: occupancy 23% = 1 block/CU ->
// 512 blocks run as TWO sequential ~138us rounds; per-chunk issue work is
// ~1us/wave, the rest is phase/barrier stall paid twice.
//
// Round 21: TWO BATCHES PER BLOCK -> one round. 1024 thr = 16 waves:
// waves 0-7 run batch blk (half 0), waves 8-15 run batch blk+256 (half 1),
// each half owning its own LDS (2 x ~52.3KB = 104.5KB < 160KB). Grid = 256
// blocks = 1/CU. Block barriers couple the halves' phases, but the halves
// do identical work. Per-SIMD waves double (2->4): stall-bound phases get
// 2x fill. Everything inside a half is r20 verbatim (rank-1 sweep-1,
// MFMA sweep-2 w/ integer self-test + VALU fallback, fused odot, 4
// barriers/chunk, Tf stride 72 f16 / G stride 68 f32).

constexpr int HID  = 64;
constexpr int INF  = 16;
constexpr int SLEN = 1024;
constexpr int BATCH = 512;
constexpr int K    = 128;            // chunk steps
constexpr int TFS  = HID + 8;        // Tf row stride (f16): 144 B
constexpr int GS   = HID + 4;        // G row stride (f32): 272 B

typedef __fp16 h2_t   __attribute__((ext_vector_type(2)));
typedef __fp16 f16x8_t __attribute__((ext_vector_type(8)));
typedef float  f32x4_t __attribute__((ext_vector_type(4)));

#if __has_builtin(__builtin_amdgcn_mfma_f32_16x16x32_f16)
#define HAVE_MFMA16 1
#else
#define HAVE_MFMA16 0
#endif

__device__ __forceinline__ float fdot(unsigned a, h2_t w, float acc) {
    return __builtin_amdgcn_fdot2(__builtin_bit_cast(h2_t, a), w, acc, false);
}

__device__ __forceinline__ float fast_tanh(float x) {
    // tanh(x) = 1 - 2/(e^{2x}+1); exact limits at +/-inf, no clamp needed.
    float e = __builtin_amdgcn_exp2f(x * 2.8853900817779268f); // 2*log2(e)
    float r = __builtin_amdgcn_rcpf(e + 1.0f);
    return fmaf(-2.0f, r, 1.0f);
}

// -expm1(-z) by series, exact to ~1e-17 for z ~ 1e-3 (avoids 1-exp cancel)
__device__ __forceinline__ float beta_of(float z) {
    return z * (1.0f - z * (0.5f - z * ((1.0f/6.0f) - z * (1.0f/24.0f))));
}

__global__ __launch_bounds__(1024) void lnn_picard5_kernel(
    const float* __restrict__ x,
    const float* __restrict__ W_in,
    const float* __restrict__ b_in,
    const float* __restrict__ W_hh,
    const float* __restrict__ W_ih,
    const float* __restrict__ bias,
    const float* __restrict__ tau,
    const float* __restrict__ W_out,
    const float* __restrict__ b_out,
    float* __restrict__ out)
{
    const int tid  = threadIdx.x;
    const int lane = tid & 63;           // hidden index
    const int wid  = tid >> 6;           // wave id 0..15
    const int half = wid >> 3;           // 0 or 1: which batch
    const int w8   = wid & 7;            // wave id within half, 0..7
    const int bb   = blockIdx.x + half * 256;    // this half's batch
    const int kg   = lane >> 4;          // k-group 0..3
    const int ln   = lane & 15;          // sub-index 0..15
    const int jb   = 16 * w8;            // tile base row

    __shared__ __fp16 Tf[2][K][TFS];     // 2 x 18 KB
    __shared__ float  G [2][K][GS];      // 2 x 34 KB
    __shared__ float  hcar[2][HID];      // carry rows
                                         // total ~104.5 KB -> 1 block/CU

    // --- per-lane setup -----------------------------------------------------
    float Wc[INF];
    #pragma unroll
    for (int k = 0; k < INF; ++k) Wc[k] = 0.0f;
    float bcomb = 0.0f;
    for (int j = 0; j < HID; ++j) {
        float wij = W_ih[lane * HID + j];
        bcomb = fmaf(wij, b_in[j], bcomb);
        #pragma unroll
        for (int k = 0; k < INF; ++k) Wc[k] = fmaf(wij, W_in[j * INF + k], Wc[k]);
    }
    const float cbase = bcomb + bias[lane];
    const float bo    = b_out[0];
    const float wo    = W_out[lane];

    const float hsub  = 1.0f / 1023.0f;
    const float rtau  = 1.0f / tau[lane];
    const float beta  = beta_of(hsub * rtau);    // 1 - e^{-dt/tau}
    const float alpha = 1.0f - beta;             // e^{-dt/tau}
    float aa2 = alpha * alpha, aa4 = aa2 * aa2, aa8 = aa4 * aa4;
    const float a16 = aa8 * aa8;                 // 16-step tile propagator

    // wh: lane's own beta-folded row (g0 eval AND the VALU fallback)
    h2_t wh[HID / 2];
    {
        const float4* w4 = (const float4*)(W_hh + lane * HID);
        #pragma unroll
        for (int q = 0; q < HID / 4; ++q) {
            float4 v = w4[q];
            wh[2*q+0] = __builtin_amdgcn_cvt_pkrtz(v.x * beta, v.y * beta);
            wh[2*q+1] = __builtin_amdgcn_cvt_pkrtz(v.z * beta, v.w * beta);
        }
    }

    // --- MFMA path: fragments + end-to-end integer self-test (r18-proven) --
    bool mfok = false;
#if HAVE_MFMA16
    f16x8_t Bw[4][2];                    // B frags: [col-tile c][k-chunk kc]
    {
        #pragma unroll
        for (int m = 0; m < 16; ++m) {
            int j = jb + m;
            Tf[half][j][lane] = (__fp16)(float)(((j * 5 + lane * 3) & 7) - 3);
        }
        #pragma unroll
        for (int c = 0; c < 4; ++c)
            #pragma unroll
            for (int kc = 0; kc < 2; ++kc) {
                int col = 16 * c + ln;
                #pragma unroll
                for (int e = 0; e < 8; ++e) {
                    int m = 32 * kc + 8 * kg + e;    // slot->k map
                    Bw[c][kc][e] = (__fp16)(float)(((col * 3 + m * 7) & 7) - 3);
                }
            }
        __syncthreads();
        {   // eval (production code): A mirrors the slot->k map
            f32x4_t acc[4];
            #pragma unroll
            for (int c = 0; c < 4; ++c) acc[c] = (f32x4_t){0.f, 0.f, 0.f, 0.f};
            const uint4* rowp = (const uint4*)(&Tf[half][jb + ln][0]);
            #pragma unroll
            for (int kc = 0; kc < 2; ++kc) {
                f16x8_t A = __builtin_bit_cast(f16x8_t, rowp[4 * kc + kg]);
                #pragma unroll
                for (int c = 0; c < 4; ++c)
                    acc[c] = __builtin_amdgcn_mfma_f32_16x16x32_f16(
                        A, Bw[c][kc], acc[c], 0, 0, 0);
            }
            #pragma unroll
            for (int c = 0; c < 4; ++c)
                #pragma unroll
                for (int r = 0; r < 4; ++r)
                    G[half][jb + 4 * kg + r][16 * c + ln] = acc[c][r];
        }
        int ok = 1;
        for (int m = 0; m < 16; ++m) {
            int j = jb + m;
            int ref = 0;
            for (int mm = 0; mm < HID; ++mm)
                ref += (((lane * 3 + mm * 7) & 7) - 3)
                     * (((j * 5 + mm * 3) & 7) - 3);
            ok &= (G[half][j][lane] == (float)ref);
        }
        mfok = (__syncthreads_and(ok) != 0);
        if (mfok) {
            #pragma unroll
            for (int c = 0; c < 4; ++c) {
                int col = 16 * c + ln;
                float bcol = beta_of(hsub * (1.0f / tau[col]));
                #pragma unroll
                for (int kc = 0; kc < 2; ++kc)
                    #pragma unroll
                    for (int e = 0; e < 8; ++e) {
                        int m = 32 * kc + 8 * kg + e;
                        Bw[c][kc][e] = (__fp16)(W_hh[col * HID + m] * bcol);
                    }
            }
        }
    }
#endif

    if (lane == 0 && w8 == 0) out[(size_t)bb * SLEN] = bo;   // step 0

    float h0 = 0.0f;                     // h at chunk start (this half)
    float cbreg[16];                     // tile's beta*c in VGPRs

    for (int ch = 0; ch < (SLEN - 1 + K - 1) / K; ++ch) {
        const int sbase = ch * K + 1;
        const int ns    = min(K, (SLEN - 1) - ch * K);   // 128 (last: 127)

        // --- proj (regs) + own t0 row --------------------------------------
        {
            #pragma unroll
            for (int m = 0; m < 16; ++m) {
                int j = jb + m;
                if (j < ns) {
                    const float4* xs =
                        (const float4*)(x + ((size_t)bb * SLEN + sbase + j) * INF);
                    float4 p0 = xs[0], p1 = xs[1], p2 = xs[2], p3 = xs[3];
                    float cA = fmaf(p0.x, Wc[0], fmaf(p0.y, Wc[1],
                               fmaf(p0.z, Wc[2], fmaf(p0.w, Wc[3], cbase))));
                    float cB = fmaf(p1.x, Wc[4], fmaf(p1.y, Wc[5],
                               fmaf(p1.z, Wc[6], p1.w * Wc[7])));
                    float cC = fmaf(p2.x, Wc[8], fmaf(p2.y, Wc[9],
                               fmaf(p2.z, Wc[10], p2.w * Wc[11])));
                    float cD = fmaf(p3.x, Wc[12], fmaf(p3.y, Wc[13],
                               fmaf(p3.z, Wc[14], p3.w * Wc[15])));
                    cbreg[m] = ((cA + cB) + (cC + cD)) * beta;
                }
            }
            Tf[half][jb][lane] = (__fp16)fast_tanh(h0);      // own t0 row
        }

        // --- sweep 1 (rank-1): g0 = Whh_b . t0, register scan --------------
        {
            const uint4* t4 = (const uint4*)Tf[half][jb];    // own row
            float a0 = 0.f, a1 = 0.f, a2_ = 0.f, a3 = 0.f;
            #pragma unroll
            for (int q = 0; q < 8; ++q) {
                uint4 r = t4[q];
                a0  = fdot(r.x, wh[4*q+0], a0);
                a1  = fdot(r.y, wh[4*q+1], a1);
                a2_ = fdot(r.z, wh[4*q+2], a2_);
                a3  = fdot(r.w, wh[4*q+3], a3);
            }
            float g0 = (a0 + a1) + (a2_ + a3);
            float L = 0.0f;
            #pragma unroll
            for (int m = 0; m < 16; ++m) {
                int j = jb + m;
                if (j < ns) {
                    L = fmaf(alpha, L, g0 + cbreg[m]);
                    G[half][j][lane] = L;                    // publish partials
                }
            }
        }
        __syncthreads();                                 // B1: sweep-1 ends

        // --- sweep-1 combine + fixup + Tf refresh --------------------------
        {
            float E = h0;
            for (int w = 0; w < w8; ++w)
                E = fmaf(a16, E, G[half][16 * w + 15][lane]);
            float p = alpha;
            #pragma unroll
            for (int m = 0; m < 16; ++m) {
                int j = jb + m;
                if (j < ns) {
                    float H = fmaf(p, E, G[half][j][lane]);
                    if (j + 1 < ns)
                        Tf[half][j + 1][lane] = (__fp16)fast_tanh(H);
                }
                p *= alpha;
            }
        }
        __syncthreads();                                 // B2: Tf refreshed

        // --- sweep 2: full eval + local scan -------------------------------
#if HAVE_MFMA16
        if (mfok) {
            f32x4_t acc[4];
            #pragma unroll
            for (int c = 0; c < 4; ++c) acc[c] = (f32x4_t){0.f,0.f,0.f,0.f};
            const uint4* rowp = (const uint4*)(&Tf[half][jb + ln][0]);
            #pragma unroll
            for (int kc = 0; kc < 2; ++kc) {
                f16x8_t A = __builtin_bit_cast(f16x8_t, rowp[4 * kc + kg]);
                #pragma unroll
                for (int c = 0; c < 4; ++c)
                    acc[c] = __builtin_amdgcn_mfma_f32_16x16x32_f16(
                        A, Bw[c][kc], acc[c], 0, 0, 0);
            }
            #pragma unroll
            for (int c = 0; c < 4; ++c)
                #pragma unroll
                for (int r = 0; r < 4; ++r)
                    G[half][jb + 4 * kg + r][16 * c + ln] = acc[c][r];
        } else
#endif
        {   // VALU eval (r16-proven)
            for (int m = 0; m < 16; ++m) {
                int j = jb + m;
                if (j < ns) {
                    const uint4* t4 = (const uint4*)Tf[half][j];
                    float a0 = 0.f, a1 = 0.f, a2_ = 0.f, a3 = 0.f;
                    #pragma unroll
                    for (int q = 0; q < 8; ++q) {
                        uint4 r = t4[q];
                        a0  = fdot(r.x, wh[4*q+0], a0);
                        a1  = fdot(r.y, wh[4*q+1], a1);
                        a2_ = fdot(r.z, wh[4*q+2], a2_);
                        a3  = fdot(r.w, wh[4*q+3], a3);
                    }
                    G[half][j][lane] = (a0 + a1) + (a2_ + a3);
                }
            }
        }
        // local scan (same-wave LDS dep only -> no barrier; r0 idiom)
        {
            float L = 0.0f;
            #pragma unroll
            for (int m = 0; m < 16; ++m) {
                int j = jb + m;
                if (j < ns) {
                    L = fmaf(alpha, L, G[half][j][lane] + cbreg[m]);
                    G[half][j][lane] = L;
                }
            }
        }
        __syncthreads();                                 // B3: sweep-2 ends

        // --- sweep-2 combine + fixup + odot (fused) + h carry --------------
        {
            float E = h0;
            for (int w = 0; w < w8; ++w)
                E = fmaf(a16, E, G[half][16 * w + 15][lane]);
            float p = alpha;
            #pragma unroll
            for (int m = 0; m < 16; ++m) {
                int j = jb + m;
                if (j < ns) {
                    float H = fmaf(p, E, G[half][j][lane]);
                    float t = (float)(__fp16)fast_tanh(H);
                    float v = t * wo;
                    #pragma unroll
                    for (int mm = 32; mm >= 1; mm >>= 1)
                        v += __shfl_xor(v, mm, 64);
                    if (lane == 0) out[(size_t)bb * SLEN + sbase + j] = v + bo;
                    if (j == ns - 1) hcar[half][lane] = H;
                }
                p *= alpha;
            }
        }
        __syncthreads();                                 // B4: h carry ready
        h0 = hcar[half][lane];
    }
}

extern "C" void kernel_launch(void* const* d_in, const int* in_sizes, int n_in,
                              void* d_out, int out_size, void* d_ws, size_t ws_size,
                              hipStream_t stream) {
    const float* x     = (const float*)d_in[0];
    const float* W_in  = (const float*)d_in[1];
    const float* b_in  = (const float*)d_in[2];
    const float* W_hh  = (const float*)d_in[3];
    const float* W_ih  = (const float*)d_in[4];
    const float* bias  = (const float*)d_in[5];
    const float* tau   = (const float*)d_in[6];
    const float* W_out = (const float*)d_in[7];
    const float* b_out = (const float*)d_in[8];
    float* out = (float*)d_out;

    lnn_picard5_kernel<<<BATCH / 2, 1024, 0, stream>>>(
        x, W_in, b_in, W_hh, W_ih, bias, tau, W_out, b_out, out);
}

// Round 22
// 330.395 us; speedup vs baseline: 1.0073x; 1.0073x over previous
//
#include <hip/hip_runtime.h>

// LiquidNeuralNetwork: B=512, S=1024, IN=16, HID=64, OUT=1.
// r21 (2 batches/block, 16 waves, 1 block/CU): occupancy 23->45.8%,
// dispatch 277->266us -- but VGPR_Count=64 forced ~315MB of scratch
// spill traffic (FETCH 220MB + WRITE 95MB vs 17/2 in r20): the compiler
// targeted 8 waves/SIMD which the 104.5KB LDS can never allow.
//
// Round 22 = r21 + __launch_bounds__(1024, 4): 16 waves/block at 1
// block/CU = 4 waves/SIMD -> VGPR cap 128 (m69), which holds the ~110
// live regs (Bw 16 + wh 16 + Wc 16 + cbreg 16 + temps) with NO spill.
// Everything else byte-identical to r21 (rank-1 sweep-1, MFMA sweep-2
// w/ integer self-test + VALU fallback, fused odot, 4 barriers/chunk,
// Tf stride 72 f16 / G stride 68 f32, conflict-free).

constexpr int HID  = 64;
constexpr int INF  = 16;
constexpr int SLEN = 1024;
constexpr int BATCH = 512;
constexpr int K    = 128;            // chunk steps
constexpr int TFS  = HID + 8;        // Tf row stride (f16): 144 B
constexpr int GS   = HID + 4;        // G row stride (f32): 272 B

typedef __fp16 h2_t   __attribute__((ext_vector_type(2)));
typedef __fp16 f16x8_t __attribute__((ext_vector_type(8)));
typedef float  f32x4_t __attribute__((ext_vector_type(4)));

#if __has_builtin(__builtin_amdgcn_mfma_f32_16x16x32_f16)
#define HAVE_MFMA16 1
#else
#define HAVE_MFMA16 0
#endif

__device__ __forceinline__ float fdot(unsigned a, h2_t w, float acc) {
    return __builtin_amdgcn_fdot2(__builtin_bit_cast(h2_t, a), w, acc, false);
}

__device__ __forceinline__ float fast_tanh(float x) {
    // tanh(x) = 1 - 2/(e^{2x}+1); exact limits at +/-inf, no clamp needed.
    float e = __builtin_amdgcn_exp2f(x * 2.8853900817779268f); // 2*log2(e)
    float r = __builtin_amdgcn_rcpf(e + 1.0f);
    return fmaf(-2.0f, r, 1.0f);
}

// -expm1(-z) by series, exact to ~1e-17 for z ~ 1e-3 (avoids 1-exp cancel)
__device__ __forceinline__ float beta_of(float z) {
    return z * (1.0f - z * (0.5f - z * ((1.0f/6.0f) - z * (1.0f/24.0f))));
}

__global__ __launch_bounds__(1024, 4) void lnn_picard6_kernel(
    const float* __restrict__ x,
    const float* __restrict__ W_in,
    const float* __restrict__ b_in,
    const float* __restrict__ W_hh,
    const float* __restrict__ W_ih,
    const float* __restrict__ bias,
    const float* __restrict__ tau,
    const float* __restrict__ W_out,
    const float* __restrict__ b_out,
    float* __restrict__ out)
{
    const int tid  = threadIdx.x;
    const int lane = tid & 63;           // hidden index
    const int wid  = tid >> 6;           // wave id 0..15
    const int half = wid >> 3;           // 0 or 1: which batch
    const int w8   = wid & 7;            // wave id within half, 0..7
    const int bb   = blockIdx.x + half * 256;    // this half's batch
    const int kg   = lane >> 4;          // k-group 0..3
    const int ln   = lane & 15;          // sub-index 0..15
    const int jb   = 16 * w8;            // tile base row

    __shared__ __fp16 Tf[2][K][TFS];     // 2 x 18 KB
    __shared__ float  G [2][K][GS];      // 2 x 34 KB
    __shared__ float  hcar[2][HID];      // carry rows
                                         // total ~104.5 KB -> 1 block/CU

    // --- per-lane setup -----------------------------------------------------
    float Wc[INF];
    #pragma unroll
    for (int k = 0; k < INF; ++k) Wc[k] = 0.0f;
    float bcomb = 0.0f;
    for (int j = 0; j < HID; ++j) {
        float wij = W_ih[lane * HID + j];
        bcomb = fmaf(wij, b_in[j], bcomb);
        #pragma unroll
        for (int k = 0; k < INF; ++k) Wc[k] = fmaf(wij, W_in[j * INF + k], Wc[k]);
    }
    const float cbase = bcomb + bias[lane];
    const float bo    = b_out[0];
    const float wo    = W_out[lane];

    const float hsub  = 1.0f / 1023.0f;
    const float rtau  = 1.0f / tau[lane];
    const float beta  = beta_of(hsub * rtau);    // 1 - e^{-dt/tau}
    const float alpha = 1.0f - beta;             // e^{-dt/tau}
    float aa2 = alpha * alpha, aa4 = aa2 * aa2, aa8 = aa4 * aa4;
    const float a16 = aa8 * aa8;                 // 16-step tile propagator

    // wh: lane's own beta-folded row (g0 eval AND the VALU fallback)
    h2_t wh[HID / 2];
    {
        const float4* w4 = (const float4*)(W_hh + lane * HID);
        #pragma unroll
        for (int q = 0; q < HID / 4; ++q) {
            float4 v = w4[q];
            wh[2*q+0] = __builtin_amdgcn_cvt_pkrtz(v.x * beta, v.y * beta);
            wh[2*q+1] = __builtin_amdgcn_cvt_pkrtz(v.z * beta, v.w * beta);
        }
    }

    // --- MFMA path: fragments + end-to-end integer self-test (r18-proven) --
    bool mfok = false;
#if HAVE_MFMA16
    f16x8_t Bw[4][2];                    // B frags: [col-tile c][k-chunk kc]
    {
        #pragma unroll
        for (int m = 0; m < 16; ++m) {
            int j = jb + m;
            Tf[half][j][lane] = (__fp16)(float)(((j * 5 + lane * 3) & 7) - 3);
        }
        #pragma unroll
        for (int c = 0; c < 4; ++c)
            #pragma unroll
            for (int kc = 0; kc < 2; ++kc) {
                int col = 16 * c + ln;
                #pragma unroll
                for (int e = 0; e < 8; ++e) {
                    int m = 32 * kc + 8 * kg + e;    // slot->k map
                    Bw[c][kc][e] = (__fp16)(float)(((col * 3 + m * 7) & 7) - 3);
                }
            }
        __syncthreads();
        {   // eval (production code): A mirrors the slot->k map
            f32x4_t acc[4];
            #pragma unroll
            for (int c = 0; c < 4; ++c) acc[c] = (f32x4_t){0.f, 0.f, 0.f, 0.f};
            const uint4* rowp = (const uint4*)(&Tf[half][jb + ln][0]);
            #pragma unroll
            for (int kc = 0; kc < 2; ++kc) {
                f16x8_t A = __builtin_bit_cast(f16x8_t, rowp[4 * kc + kg]);
                #pragma unroll
                for (int c = 0; c < 4; ++c)
                    acc[c] = __builtin_amdgcn_mfma_f32_16x16x32_f16(
                        A, Bw[c][kc], acc[c], 0, 0, 0);
            }
            #pragma unroll
            for (int c = 0; c < 4; ++c)
                #pragma unroll
                for (int r = 0; r < 4; ++r)
                    G[half][jb + 4 * kg + r][16 * c + ln] = acc[c][r];
        }
        int ok = 1;
        for (int m = 0; m < 16; ++m) {
            int j = jb + m;
            int ref = 0;
            for (int mm = 0; mm < HID; ++mm)
                ref += (((lane * 3 + mm * 7) & 7) - 3)
                     * (((j * 5 + mm * 3) & 7) - 3);
            ok &= (G[half][j][lane] == (float)ref);
        }
        mfok = (__syncthreads_and(ok) != 0);
        if (mfok) {
            #pragma unroll
            for (int c = 0; c < 4; ++c) {
                int col = 16 * c + ln;
                float bcol = beta_of(hsub * (1.0f / tau[col]));
                #pragma unroll
                for (int kc = 0; kc < 2; ++kc)
                    #pragma unroll
                    for (int e = 0; e < 8; ++e) {
                        int m = 32 * kc + 8 * kg + e;
                        Bw[c][kc][e] = (__fp16)(W_hh[col * HID + m] * bcol);
                    }
            }
        }
    }
#endif

    if (lane == 0 && w8 == 0) out[(size_t)bb * SLEN] = bo;   // step 0

    float h0 = 0.0f;                     // h at chunk start (this half)
    float cbreg[16];                     // tile's beta*c in VGPRs

    for (int ch = 0; ch < (SLEN - 1 + K - 1) / K; ++ch) {
        const int sbase = ch * K + 1;
        const int ns    = min(K, (SLEN - 1) - ch * K);   // 128 (last: 127)

        // --- proj (regs) + own t0 row --------------------------------------
        {
            #pragma unroll
            for (int m = 0; m < 16; ++m) {
                int j = jb + m;
                if (j < ns) {
                    const float4* xs =
                        (const float4*)(x + ((size_t)bb * SLEN + sbase + j) * INF);
                    float4 p0 = xs[0], p1 = xs[1], p2 = xs[2], p3 = xs[3];
                    float cA = fmaf(p0.x, Wc[0], fmaf(p0.y, Wc[1],
                               fmaf(p0.z, Wc[2], fmaf(p0.w, Wc[3], cbase))));
                    float cB = fmaf(p1.x, Wc[4], fmaf(p1.y, Wc[5],
                               fmaf(p1.z, Wc[6], p1.w * Wc[7])));
                    float cC = fmaf(p2.x, Wc[8], fmaf(p2.y, Wc[9],
                               fmaf(p2.z, Wc[10], p2.w * Wc[11])));
                    float cD = fmaf(p3.x, Wc[12], fmaf(p3.y, Wc[13],
                               fmaf(p3.z, Wc[14], p3.w * Wc[15])));
                    cbreg[m] = ((cA + cB) + (cC + cD)) * beta;
                }
            }
            Tf[half][jb][lane] = (__fp16)fast_tanh(h0);      // own t0 row
        }

        // --- sweep 1 (rank-1): g0 = Whh_b . t0, register scan --------------
        {
            const uint4* t4 = (const uint4*)Tf[half][jb];    // own row
            float a0 = 0.f, a1 = 0.f, a2_ = 0.f, a3 = 0.f;
            #pragma unroll
            for (int q = 0; q < 8; ++q) {
                uint4 r = t4[q];
                a0  = fdot(r.x, wh[4*q+0], a0);
                a1  = fdot(r.y, wh[4*q+1], a1);
                a2_ = fdot(r.z, wh[4*q+2], a2_);
                a3  = fdot(r.w, wh[4*q+3], a3);
            }
            float g0 = (a0 + a1) + (a2_ + a3);
            float L = 0.0f;
            #pragma unroll
            for (int m = 0; m < 16; ++m) {
                int j = jb + m;
                if (j < ns) {
                    L = fmaf(alpha, L, g0 + cbreg[m]);
                    G[half][j][lane] = L;                    // publish partials
                }
            }
        }
        __syncthreads();                                 // B1: sweep-1 ends

        // --- sweep-1 combine + fixup + Tf refresh --------------------------
        {
            float E = h0;
            for (int w = 0; w < w8; ++w)
                E = fmaf(a16, E, G[half][16 * w + 15][lane]);
            float p = alpha;
            #pragma unroll
            for (int m = 0; m < 16; ++m) {
                int j = jb + m;
                if (j < ns) {
                    float H = fmaf(p, E, G[half][j][lane]);
                    if (j + 1 < ns)
                        Tf[half][j + 1][lane] = (__fp16)fast_tanh(H);
                }
                p *= alpha;
            }
        }
        __syncthreads();                                 // B2: Tf refreshed

        // --- sweep 2: full eval + local scan -------------------------------
#if HAVE_MFMA16
        if (mfok) {
            f32x4_t acc[4];
            #pragma unroll
            for (int c = 0; c < 4; ++c) acc[c] = (f32x4_t){0.f,0.f,0.f,0.f};
            const uint4* rowp = (const uint4*)(&Tf[half][jb + ln][0]);
            #pragma unroll
            for (int kc = 0; kc < 2; ++kc) {
                f16x8_t A = __builtin_bit_cast(f16x8_t, rowp[4 * kc + kg]);
                #pragma unroll
                for (int c = 0; c < 4; ++c)
                    acc[c] = __builtin_amdgcn_mfma_f32_16x16x32_f16(
                        A, Bw[c][kc], acc[c], 0, 0, 0);
            }
            #pragma unroll
            for (int c = 0; c < 4; ++c)
                #pragma unroll
                for (int r = 0; r < 4; ++r)
                    G[half][jb + 4 * kg + r][16 * c + ln] = acc[c][r];
        } else
#endif
        {   // VALU eval (r16-proven)
            for (int m = 0; m < 16; ++m) {
                int j = jb + m;
                if (j < ns) {
                    const uint4* t4 = (const uint4*)Tf[half][j];
                    float a0 = 0.f, a1 = 0.f, a2_ = 0.f, a3 = 0.f;
                    #pragma unroll
                    for (int q = 0; q < 8; ++q) {
                        uint4 r = t4[q];
                        a0  = fdot(r.x, wh[4*q+0], a0);
                        a1  = fdot(r.y, wh[4*q+1], a1);
                        a2_ = fdot(r.z, wh[4*q+2], a2_);
                        a3  = fdot(r.w, wh[4*q+3], a3);
                    }
                    G[half][j][lane] = (a0 + a1) + (a2_ + a3);
                }
            }
        }
        // local scan (same-wave LDS dep only -> no barrier; r0 idiom)
        {
            float L = 0.0f;
            #pragma unroll
            for (int m = 0; m < 16; ++m) {
                int j = jb + m;
                if (j < ns) {
                    L = fmaf(alpha, L, G[half][j][lane] + cbreg[m]);
                    G[half][j][lane] = L;
                }
            }
        }
        __syncthreads();                                 // B3: sweep-2 ends

        // --- sweep-2 combine + fixup + odot (fused) + h carry --------------
        {
            float E = h0;
            for (int w = 0; w < w8; ++w)
                E = fmaf(a16, E, G[half][16 * w + 15][lane]);
            float p = alpha;
            #pragma unroll
            for (int m = 0; m < 16; ++m) {
                int j = jb + m;
                if (j < ns) {
                    float H = fmaf(p, E, G[half][j][lane]);
                    float t = (float)(__fp16)fast_tanh(H);
                    float v = t * wo;
                    #pragma unroll
                    for (int mm = 32; mm >= 1; mm >>= 1)
                        v += __shfl_xor(v, mm, 64);
                    if (lane == 0) out[(size_t)bb * SLEN + sbase + j] = v + bo;
                    if (j == ns - 1) hcar[half][lane] = H;
                }
                p *= alpha;
            }
        }
        __syncthreads();                                 // B4: h carry ready
        h0 = hcar[half][lane];
    }
}

extern "C" void kernel_launch(void* const* d_in, const int* in_sizes, int n_in,
                              void* d_out, int out_size, void* d_ws, size_t ws_size,
                              hipStream_t stream) {
    const float* x     = (const float*)d_in[0];
    const float* W_in  = (const float*)d_in[1];
    const float* b_in  = (const float*)d_in[2];
    const float* W_hh  = (const float*)d_in[3];
    const float* W_ih  = (const float*)d_in[4];
    const float* bias  = (const float*)d_in[5];
    const float* tau   = (const float*)d_in[6];
    const float* W_out = (const float*)d_in[7];
    const float* b_out = (const float*)d_in[8];
    float* out = (float*)d_out;

    lnn_picard6_kernel<<<BATCH / 2, 1024, 0, stream>>>(
        x, W_in, b_in, W_hh, W_ih, bias, tau, W_out, b_out, out);
}